// Round 18
// baseline (771.664 us; speedup 1.0000x reference)
//
#include <hip/hip_runtime.h>
#include <hip/hip_bf16.h>

#define EPSV 1e-5f
#define SLOPE 0.1f

typedef __attribute__((ext_vector_type(8))) unsigned short ushort8v;
typedef __attribute__((ext_vector_type(8))) short bf16x8;
typedef __attribute__((ext_vector_type(4))) float f32x4;

static __device__ inline unsigned short f2bf(float f) {
    __hip_bfloat16 b = __float2bfloat16(f);
    return *reinterpret_cast<unsigned short*>(&b);
}
static __device__ inline float bf2f(unsigned short u) {
    return __uint_as_float(((unsigned)u) << 16);
}

// ---------------- degree ----------------
__global__ __launch_bounds__(256) void k_count(const int* __restrict__ col,
                                               unsigned* __restrict__ cnt, int E) {
    int e = blockIdx.x * 256 + threadIdx.x;
    if (e < E) atomicAdd(&cnt[col[e]], 1u);
}

// ---------------- chunk sums + dinv (fused) ----------------
__global__ __launch_bounds__(256) void k_chunk_sum(const unsigned* __restrict__ cnt, int N,
                                                   unsigned* __restrict__ bsum,
                                                   float* __restrict__ dinv) {
    __shared__ unsigned ls[256];
    int base = blockIdx.x * 1024;
    unsigned s = 0;
    for (int i = threadIdx.x; i < 1024; i += 256) {
        int idx = base + i;
        if (idx < N) {
            unsigned c = cnt[idx];
            s += c;
            dinv[idx] = rsqrtf((float)c + 2.0f);
        }
    }
    ls[threadIdx.x] = s;
    __syncthreads();
    for (int st = 128; st > 0; st >>= 1) {
        if (threadIdx.x < st) ls[threadIdx.x] += ls[threadIdx.x + st];
        __syncthreads();
    }
    if (threadIdx.x == 0) bsum[blockIdx.x] = ls[0];
}

// ---------------- parallel scan of chunk sums (nb <= 128) ----------------
__global__ __launch_bounds__(128) void k_scan_bsum(unsigned* __restrict__ bsum, int nb) {
    const int t = threadIdx.x;
    unsigned v = (t < nb) ? bsum[t] : 0u;
    unsigned s = v;
    for (int d = 1; d < 64; d <<= 1) {
        unsigned y = __shfl_up(s, d, 64);
        if ((t & 63) >= d) s += y;
    }
    __shared__ unsigned wtot;
    if (t == 63) wtot = s;
    __syncthreads();
    unsigned base = (t >= 64) ? wtot : 0u;
    if (t < nb) bsum[t] = base + s - v;  // exclusive
}

__global__ __launch_bounds__(256) void k_scan_chunks(const unsigned* __restrict__ cnt, int N,
                                                     const unsigned* __restrict__ bsum,
                                                     int* __restrict__ off,
                                                     int* __restrict__ cursor, int E) {
    __shared__ unsigned ls[256];
    int base = blockIdx.x * 1024;
    unsigned v[4];
    unsigned s = 0;
#pragma unroll
    for (int j = 0; j < 4; j++) {
        int idx = base + threadIdx.x * 4 + j;
        v[j] = (idx < N) ? cnt[idx] : 0u;
        s += v[j];
    }
    ls[threadIdx.x] = s;
    __syncthreads();
    if (threadIdx.x == 0) {
        unsigned acc = bsum[blockIdx.x];
        for (int i = 0; i < 256; i++) { unsigned t = ls[i]; ls[i] = acc; acc += t; }
    }
    __syncthreads();
    unsigned acc = ls[threadIdx.x];
#pragma unroll
    for (int j = 0; j < 4; j++) {
        int idx = base + threadIdx.x * 4 + j;
        if (idx < N) { off[idx] = (int)acc; cursor[idx] = (int)acc; }
        acc += v[j];
    }
    if (base + threadIdx.x * 4 <= N - 1 && N - 1 < base + threadIdx.x * 4 + 4) off[N] = E;
}

// ---------------- counting-sort placement: (row, norm) grouped by col ----------------
__global__ __launch_bounds__(256) void k_place(const int* __restrict__ row,
                                               const int* __restrict__ col,
                                               const float* __restrict__ dinv,
                                               int* __restrict__ cursor,
                                               int2* __restrict__ spack, int E) {
    int e = blockIdx.x * 256 + threadIdx.x;
    if (e >= E) return;
    int r = row[e], c = col[e];
    int pos = atomicAdd(&cursor[c], 1);
    spack[pos] = make_int2(r, __float_as_int(dinv[r] * dinv[c]));
}

// ---------------- degree histogram (256 bins, clamped) ----------------
__global__ __launch_bounds__(256) void k_hist(const unsigned* __restrict__ cnt, int N,
                                              unsigned* __restrict__ hist) {
    __shared__ unsigned lh[256];
    lh[threadIdx.x] = 0;
    __syncthreads();
    int n = blockIdx.x * 256 + threadIdx.x;
    if (n < N) {
        unsigned d = cnt[n]; if (d > 255u) d = 255u;
        atomicAdd(&lh[d], 1u);
    }
    __syncthreads();
    if (lh[threadIdx.x]) atomicAdd(&hist[threadIdx.x], lh[threadIdx.x]);
}

// ---------------- scan 256 bins -> binCur ----------------
__global__ __launch_bounds__(256) void k_permscan(const unsigned* __restrict__ hist,
                                                  int* __restrict__ binCur) {
    const int t = threadIdx.x;
    unsigned v = hist[t];
    unsigned s = v;
    for (int d = 1; d < 64; d <<= 1) {
        unsigned y = __shfl_up(s, d, 64);
        if ((t & 63) >= d) s += y;
    }
    __shared__ unsigned wtot[4];
    if ((t & 63) == 63) wtot[t >> 6] = s;
    __syncthreads();
    unsigned carry = 0;
    for (int w = 0; w < (t >> 6); w++) carry += wtot[w];
    binCur[t] = (int)(carry + s - v);  // exclusive
}

// ---------------- place nodes into degree-sorted perm (packed int4) ----------------
__global__ __launch_bounds__(256) void k_permplace(const unsigned* __restrict__ cnt,
                                                   const int* __restrict__ off,
                                                   const float* __restrict__ dinv,
                                                   int* __restrict__ binCur,
                                                   int4* __restrict__ perm4, int N) {
    int n = blockIdx.x * 256 + threadIdx.x;
    if (n >= N) return;
    unsigned d = cnt[n]; if (d > 255u) d = 255u;
    int pos = atomicAdd(&binCur[d], 1);
    perm4[pos] = make_int4(n, off[n], off[n + 1], __float_as_int(dinv[n]));
}

// ---------------- weight prep: wT[n][k] = bf16(W[k][n]), 2 matrices ----------------
__global__ __launch_bounds__(256) void k_prepw(const float* __restrict__ W1,
                                               const float* __restrict__ W2,
                                               unsigned short* __restrict__ wT) {
    int m = blockIdx.x >> 4;                 // matrix 0..1
    int idx = (blockIdx.x & 15) * 256 + threadIdx.x;  // 0..4095 float4s
    const float* W = (m == 0) ? W1 : W2;
    unsigned short* T = wT + (size_t)m * 16384;
    int k = idx >> 5, n4 = (idx & 31) * 4;
    float4 v = *(const float4*)(W + (size_t)k * 128 + n4);
    T[(size_t)(n4 + 0) * 128 + k] = f2bf(v.x);
    T[(size_t)(n4 + 1) * 128 + k] = f2bf(v.y);
    T[(size_t)(n4 + 2) * 128 + k] = f2bf(v.z);
    T[(size_t)(n4 + 3) * 128 + k] = f2bf(v.w);
}

// ---------------- MFMA GEMM: Y[N,128] = X[N,128] @ W[128,128] -> bf16 ----------------
// MODE 0: f32 in. MODE 1: bf16 in with BN+leaky fused.
template <int MODE>
__global__ __launch_bounds__(256) void k_gemm_m(const void* __restrict__ Xv,
                                                const unsigned short* __restrict__ wT,
                                                const float* __restrict__ sums, float invN,
                                                const float* __restrict__ bnw,
                                                const float* __restrict__ bnb,
                                                void* __restrict__ Yv, int N) {
    __shared__ unsigned short xs[64][136];   // +8 pad: conflict-free b128 reads
    __shared__ float sc[128], sb[128];
    const int tid = threadIdx.x;
    if (MODE == 1) {
        if (tid < 128) {
            float mu = sums[tid] * invN;
            float var = sums[128 + tid] * invN - mu * mu;
            float s = rsqrtf(var + EPSV) * bnw[tid];
            sc[tid] = s;
            sb[tid] = bnb[tid] - mu * s;
        }
        __syncthreads();
    }
    const int base = blockIdx.x * 64;
    if (MODE == 1) {
        const unsigned short* Xh = (const unsigned short*)Xv;
        for (int i = tid; i < 1024; i += 256) {
            int r = i >> 4, c8 = (i & 15) * 8;
            int row = base + r; if (row >= N) row = N - 1;
            ushort8v v = *(const ushort8v*)(Xh + (size_t)row * 128 + c8);
            ushort8v o;
#pragma unroll
            for (int j = 0; j < 8; j++) {
                float f = fmaf(bf2f(v[j]), sc[c8 + j], sb[c8 + j]);
                f = f > 0.f ? f : SLOPE * f;
                o[j] = f2bf(f);
            }
            *(ushort8v*)(&xs[r][c8]) = o;
        }
    } else {
        const float* X = (const float*)Xv;
        for (int i = tid; i < 2048; i += 256) {
            int r = i >> 5, c4 = i & 31;
            int row = base + r; if (row >= N) row = N - 1;
            float4 v = ((const float4*)(X + (size_t)row * 128))[c4];
            ushort4 o;
            o.x = f2bf(v.x); o.y = f2bf(v.y); o.z = f2bf(v.z); o.w = f2bf(v.w);
            *(ushort4*)(&xs[r][c4 * 4]) = o;
        }
    }
    __syncthreads();

    const int lane = tid & 63;
    const int m0 = (tid >> 6) * 16;          // wave's 16 rows in tile
    const int mr = lane & 15;
    const int kg = lane >> 4;                // 0..3
    f32x4 acc[8];
#pragma unroll
    for (int nf = 0; nf < 8; nf++) acc[nf] = (f32x4){0.f, 0.f, 0.f, 0.f};

#pragma unroll
    for (int kt = 0; kt < 4; kt++) {
        bf16x8 a = *(const bf16x8*)(&xs[m0 + mr][kt * 32 + kg * 8]);
#pragma unroll
        for (int nf = 0; nf < 8; nf++) {
            bf16x8 b = *(const bf16x8*)(wT + (size_t)(nf * 16 + mr) * 128 + kt * 32 + kg * 8);
            acc[nf] = __builtin_amdgcn_mfma_f32_16x16x32_bf16(a, b, acc[nf], 0, 0, 0);
        }
    }

    // C/D layout: col = lane&15, row = (lane>>4)*4 + r; repack via LDS -> coalesced stores
    __syncthreads();
#pragma unroll
    for (int nf = 0; nf < 8; nf++) {
#pragma unroll
        for (int r = 0; r < 4; r++) {
            xs[m0 + kg * 4 + r][nf * 16 + mr] = f2bf(acc[nf][r]);
        }
    }
    __syncthreads();
    unsigned short* Yh = (unsigned short*)Yv;
    for (int i = tid; i < 1024; i += 256) {
        int r = i >> 4, c8 = (i & 15) * 8;
        int row = base + r;
        if (row < N)
            *(ushort8v*)(Yh + (size_t)row * 128 + c8) = *(const ushort8v*)(&xs[r][c8]);
    }
}

// ---------------- CSR aggregation: 16-lane group owns a node (degree-balanced) ----------------
// perm4[idx] = (n, off[n], off[n+1], dinv[n]); degree-sorted round-robin balances waves.
__global__ __launch_bounds__(256) void k_agg5(const unsigned short* __restrict__ xwh,
                                              const int4* __restrict__ perm4,
                                              const int2* __restrict__ spack,
                                              const float* __restrict__ bias,
                                              unsigned short* __restrict__ h,
                                              float* __restrict__ sums, int N) {
    __shared__ float ls1[128], ls2[128];
    const int tid = threadIdx.x;
    if (tid < 128) { ls1[tid] = 0.f; ls2[tid] = 0.f; }
    __syncthreads();

    const int q = tid & 15;
    const int grp = (blockIdx.x * 256 + tid) >> 4;
    const int nGrp = gridDim.x * 16;

    float bj[8];
#pragma unroll
    for (int j = 0; j < 8; j++) bj[j] = bias[q * 8 + j];
    float st1[8] = {0, 0, 0, 0, 0, 0, 0, 0};
    float st2[8] = {0, 0, 0, 0, 0, 0, 0, 0};

    for (int idx = grp; idx < N; idx += nGrp) {
        int4 pm = perm4[idx];
        const int n = pm.x, s = pm.y, e = pm.z;
        const float dc = __int_as_float(pm.w);
        float a[8] = {0, 0, 0, 0, 0, 0, 0, 0};
        int i = s;
        for (; i + 8 <= e; i += 8) {
            int2 p0 = spack[i + 0], p1 = spack[i + 1], p2 = spack[i + 2], p3 = spack[i + 3];
            int2 p4 = spack[i + 4], p5 = spack[i + 5], p6 = spack[i + 6], p7 = spack[i + 7];
            ushort8v v0 = *(const ushort8v*)(xwh + (size_t)p0.x * 128 + q * 8);
            ushort8v v1 = *(const ushort8v*)(xwh + (size_t)p1.x * 128 + q * 8);
            ushort8v v2 = *(const ushort8v*)(xwh + (size_t)p2.x * 128 + q * 8);
            ushort8v v3 = *(const ushort8v*)(xwh + (size_t)p3.x * 128 + q * 8);
            ushort8v v4 = *(const ushort8v*)(xwh + (size_t)p4.x * 128 + q * 8);
            ushort8v v5 = *(const ushort8v*)(xwh + (size_t)p5.x * 128 + q * 8);
            ushort8v v6 = *(const ushort8v*)(xwh + (size_t)p6.x * 128 + q * 8);
            ushort8v v7 = *(const ushort8v*)(xwh + (size_t)p7.x * 128 + q * 8);
            float n0 = __int_as_float(p0.y), n1 = __int_as_float(p1.y);
            float n2 = __int_as_float(p2.y), n3 = __int_as_float(p3.y);
            float n4 = __int_as_float(p4.y), n5 = __int_as_float(p5.y);
            float n6 = __int_as_float(p6.y), n7 = __int_as_float(p7.y);
#pragma unroll
            for (int j = 0; j < 8; j++) {
                float t = fmaf(n0, bf2f(v0[j]), fmaf(n1, bf2f(v1[j]),
                          fmaf(n2, bf2f(v2[j]), n3 * bf2f(v3[j]))));
                float u = fmaf(n4, bf2f(v4[j]), fmaf(n5, bf2f(v5[j]),
                          fmaf(n6, bf2f(v6[j]), n7 * bf2f(v7[j]))));
                a[j] += t + u;
            }
        }
        for (; i + 4 <= e; i += 4) {
            int2 p0 = spack[i + 0], p1 = spack[i + 1], p2 = spack[i + 2], p3 = spack[i + 3];
            ushort8v v0 = *(const ushort8v*)(xwh + (size_t)p0.x * 128 + q * 8);
            ushort8v v1 = *(const ushort8v*)(xwh + (size_t)p1.x * 128 + q * 8);
            ushort8v v2 = *(const ushort8v*)(xwh + (size_t)p2.x * 128 + q * 8);
            ushort8v v3 = *(const ushort8v*)(xwh + (size_t)p3.x * 128 + q * 8);
            float n0 = __int_as_float(p0.y), n1 = __int_as_float(p1.y);
            float n2 = __int_as_float(p2.y), n3 = __int_as_float(p3.y);
#pragma unroll
            for (int j = 0; j < 8; j++) {
                a[j] += fmaf(n0, bf2f(v0[j]), fmaf(n1, bf2f(v1[j]),
                        fmaf(n2, bf2f(v2[j]), n3 * bf2f(v3[j]))));
            }
        }
        for (; i < e; ++i) {
            int2 p = spack[i];
            ushort8v v = *(const ushort8v*)(xwh + (size_t)p.x * 128 + q * 8);
            float nm = __int_as_float(p.y);
#pragma unroll
            for (int j = 0; j < 8; j++) a[j] = fmaf(nm, bf2f(v[j]), a[j]);
        }
        float sl = 2.f * dc * dc;
        ushort8v xv = *(const ushort8v*)(xwh + (size_t)n * 128 + q * 8);
        ushort8v ov;
#pragma unroll
        for (int j = 0; j < 8; j++) {
            float o = fmaf(sl, bf2f(xv[j]), a[j]) + bj[j];
            st1[j] += o;
            st2[j] += o * o;
            ov[j] = f2bf(o);
        }
        *(ushort8v*)(h + (size_t)n * 128 + q * 8) = ov;
    }
#pragma unroll
    for (int j = 0; j < 8; j++) {
        atomicAdd(&ls1[q * 8 + j], st1[j]);
        atomicAdd(&ls2[q * 8 + j], st2[j]);
    }
    __syncthreads();
    if (tid < 128) {
        atomicAdd(&sums[tid], ls1[tid]);
        atomicAdd(&sums[128 + tid], ls2[tid]);
    }
}

// ---------------- fused tail: BN2+leaky+segment-max+final GEMM ----------------
// one wave per graph; batch is sorted -> binary search node range
__global__ __launch_bounds__(256) void k_tail(const unsigned short* __restrict__ h,
                                              const int* __restrict__ batch,
                                              const float* __restrict__ sums, float invN,
                                              const float* __restrict__ bnw,
                                              const float* __restrict__ bnb,
                                              const float* __restrict__ Wf,
                                              const float* __restrict__ bf,
                                              float* __restrict__ out, int N, int G) {
    const int lane = threadIdx.x & 63;
    const int g = blockIdx.x * 4 + (threadIdx.x >> 6);
    if (g >= G) return;
    const int f0 = lane, f1 = lane + 64;
    float mu0 = sums[f0] * invN;
    float var0 = sums[128 + f0] * invN - mu0 * mu0;
    float sc0 = rsqrtf(var0 + EPSV) * bnw[f0];
    float sb0 = bnb[f0] - mu0 * sc0;
    float mu1 = sums[f1] * invN;
    float var1 = sums[128 + f1] * invN - mu1 * mu1;
    float sc1 = rsqrtf(var1 + EPSV) * bnw[f1];
    float sb1 = bnb[f1] - mu1 * sc1;

    int lo, hi;
    { int a = 0, b = N; while (a < b) { int m = (a + b) >> 1; if (batch[m] < g) a = m + 1; else b = m; } lo = a; }
    { int a = lo, b = N; while (a < b) { int m = (a + b) >> 1; if (batch[m] < g + 1) a = m + 1; else b = m; } hi = a; }

    float m0 = -__builtin_inff(), m1 = -__builtin_inff();
    for (int n = lo; n < hi; n++) {
        float v0 = fmaf(bf2f(h[(size_t)n * 128 + f0]), sc0, sb0);
        float v1 = fmaf(bf2f(h[(size_t)n * 128 + f1]), sc1, sb1);
        v0 = v0 > 0.f ? v0 : SLOPE * v0;
        v1 = v1 > 0.f ? v1 : SLOPE * v1;
        m0 = fmaxf(m0, v0);
        m1 = fmaxf(m1, v1);
    }
    if (lo >= hi) { m0 = 0.f; m1 = 0.f; }  // empty graph -> pooled 0

    float o0 = bf[f0], o1 = bf[f1];
    for (int k = 0; k < 64; k++) {
        float vk = __shfl(m0, k, 64);
        o0 = fmaf(vk, Wf[(size_t)k * 128 + f0], o0);
        o1 = fmaf(vk, Wf[(size_t)k * 128 + f1], o1);
    }
    for (int k = 0; k < 64; k++) {
        float vk = __shfl(m1, k, 64);
        o0 = fmaf(vk, Wf[(size_t)(k + 64) * 128 + f0], o0);
        o1 = fmaf(vk, Wf[(size_t)(k + 64) * 128 + f1], o1);
    }
    out[(size_t)g * 128 + f0] = o0;
    out[(size_t)g * 128 + f1] = o1;
}

extern "C" void kernel_launch(void* const* d_in, const int* in_sizes, int n_in,
                              void* d_out, int out_size, void* d_ws, size_t ws_size,
                              hipStream_t stream) {
    const float* x     = (const float*)d_in[0];
    const int*   ei    = (const int*)d_in[1];
    const int*   batch = (const int*)d_in[2];
    const float* W1    = (const float*)d_in[3];
    const float* b1    = (const float*)d_in[4];
    const float* bn1w  = (const float*)d_in[5];
    const float* bn1b  = (const float*)d_in[6];
    const float* W2    = (const float*)d_in[7];
    const float* b2    = (const float*)d_in[8];
    const float* bn2w  = (const float*)d_in[9];
    const float* bn2b  = (const float*)d_in[10];
    const float* Wf    = (const float*)d_in[11];
    const float* bf    = (const float*)d_in[12];

    const int N = in_sizes[0] / 128;
    const int E = in_sizes[1] / 2;
    const int G = out_size / 128;
    const int* rowp = ei;
    const int* colp = ei + E;
    float* out = (float*)d_out;
    const float invN = 1.0f / N;

    char* w = (char*)d_ws;
    unsigned short* bufAh = (unsigned short*)w; w += (size_t)N * 128 * 2;  // bf16 xw
    unsigned short* bufBh = (unsigned short*)w; w += (size_t)N * 128 * 2;  // bf16 h
    float*    dinv   = (float*)w;    w += (size_t)N * 4;
    unsigned* cnt    = (unsigned*)w; w += (size_t)N * 4;
    int*      cursor = (int*)w;      w += (size_t)N * 4;
    int*      off    = (int*)w;      w += (size_t)(N + 4) * 4;
    unsigned* bsum   = (unsigned*)w; w += 1024 * 4;
    int2*     spack  = (int2*)w;     w += (size_t)E * 8;
    float*    sums   = (float*)w;    w += 512 * 4;                         // sums1 | sums2
    unsigned* hist   = (unsigned*)w; w += 256 * 4;                         // zeroed with sums
    int*      binCur = (int*)w;      w += 256 * 4;
    int4*     perm4  = (int4*)w;     w += (size_t)N * 16;
    unsigned short* wT = (unsigned short*)w; w += 2 * 16384 * 2;           // wT1|wT2

    float* sums1 = sums;
    float* sums2 = sums + 256;
    const int nb = (N + 1023) / 1024;
    const int nblk = (N + 255) / 256;

    // ---- prep (graph CSR + degree-balanced perm + bf16 transposed weights) ----
    hipMemsetAsync(cnt, 0, (size_t)N * 4, stream);
    hipMemsetAsync(sums, 0, (512 + 256) * 4, stream);   // sums + hist
    k_prepw<<<32, 256, 0, stream>>>(W1, W2, wT);
    k_count<<<(E + 255) / 256, 256, 0, stream>>>(colp, cnt, E);
    k_chunk_sum<<<nb, 256, 0, stream>>>(cnt, N, bsum, dinv);
    k_scan_bsum<<<1, 128, 0, stream>>>(bsum, nb);
    k_scan_chunks<<<nb, 256, 0, stream>>>(cnt, N, bsum, off, cursor, E);
    k_place<<<(E + 255) / 256, 256, 0, stream>>>(rowp, colp, dinv, cursor, spack, E);
    k_hist<<<nblk, 256, 0, stream>>>(cnt, N, hist);
    k_permscan<<<1, 256, 0, stream>>>(hist, binCur);
    k_permplace<<<nblk, 256, 0, stream>>>(cnt, off, dinv, binCur, perm4, N);

    const int aggBlocks = 2048;
    const int gemmGrid = (N + 63) / 64;

    // ---- layer 1 ----
    k_gemm_m<0><<<gemmGrid, 256, 0, stream>>>(x, wT, nullptr, 0.f, nullptr, nullptr,
                                              bufAh, N);
    k_agg5<<<aggBlocks, 256, 0, stream>>>(bufAh, perm4, spack, b1, bufBh, sums1, N);

    // ---- layer 2 (BN1 fused into GEMM staging, bf16 input) ----
    k_gemm_m<1><<<gemmGrid, 256, 0, stream>>>(bufBh, wT + 16384, sums1, invN, bn1w, bn1b,
                                              bufAh, N);
    k_agg5<<<aggBlocks, 256, 0, stream>>>(bufAh, perm4, spack, b2, bufBh, sums2, N);

    // ---- fused tail: BN2 + leaky + segment-max + final GEMM ----
    k_tail<<<(G + 3) / 4, 256, 0, stream>>>(bufBh, batch, sums2, invN, bn2w, bn2b,
                                            Wf, bf, out, N, G);
}

// Round 19
// 425.457 us; speedup vs baseline: 1.8137x; 1.8137x over previous
//
#include <hip/hip_runtime.h>
#include <hip/hip_bf16.h>

#define EPSV 1e-5f
#define SLOPE 0.1f

typedef __attribute__((ext_vector_type(8))) unsigned short ushort8v;
typedef __attribute__((ext_vector_type(8))) short bf16x8;
typedef __attribute__((ext_vector_type(4))) float f32x4;

static __device__ inline unsigned short f2bf(float f) {
    __hip_bfloat16 b = __float2bfloat16(f);
    return *reinterpret_cast<unsigned short*>(&b);
}
static __device__ inline float bf2f(unsigned short u) {
    return __uint_as_float(((unsigned)u) << 16);
}

// ---------------- degree ----------------
__global__ __launch_bounds__(256) void k_count(const int* __restrict__ col,
                                               unsigned* __restrict__ cnt, int E) {
    int e = blockIdx.x * 256 + threadIdx.x;
    if (e < E) atomicAdd(&cnt[col[e]], 1u);
}

// ---------------- chunk sums + dinv (fused) ----------------
__global__ __launch_bounds__(256) void k_chunk_sum(const unsigned* __restrict__ cnt, int N,
                                                   unsigned* __restrict__ bsum,
                                                   float* __restrict__ dinv) {
    __shared__ unsigned ls[256];
    int base = blockIdx.x * 1024;
    unsigned s = 0;
    for (int i = threadIdx.x; i < 1024; i += 256) {
        int idx = base + i;
        if (idx < N) {
            unsigned c = cnt[idx];
            s += c;
            dinv[idx] = rsqrtf((float)c + 2.0f);
        }
    }
    ls[threadIdx.x] = s;
    __syncthreads();
    for (int st = 128; st > 0; st >>= 1) {
        if (threadIdx.x < st) ls[threadIdx.x] += ls[threadIdx.x + st];
        __syncthreads();
    }
    if (threadIdx.x == 0) bsum[blockIdx.x] = ls[0];
}

// ---------------- parallel scan of chunk sums (nb <= 128) ----------------
__global__ __launch_bounds__(128) void k_scan_bsum(unsigned* __restrict__ bsum, int nb) {
    const int t = threadIdx.x;
    unsigned v = (t < nb) ? bsum[t] : 0u;
    unsigned s = v;
    for (int d = 1; d < 64; d <<= 1) {
        unsigned y = __shfl_up(s, d, 64);
        if ((t & 63) >= d) s += y;
    }
    __shared__ unsigned wtot;
    if (t == 63) wtot = s;
    __syncthreads();
    unsigned base = (t >= 64) ? wtot : 0u;
    if (t < nb) bsum[t] = base + s - v;  // exclusive
}

__global__ __launch_bounds__(256) void k_scan_chunks(const unsigned* __restrict__ cnt, int N,
                                                     const unsigned* __restrict__ bsum,
                                                     int* __restrict__ off,
                                                     int* __restrict__ cursor, int E) {
    __shared__ unsigned ls[256];
    int base = blockIdx.x * 1024;
    unsigned v[4];
    unsigned s = 0;
#pragma unroll
    for (int j = 0; j < 4; j++) {
        int idx = base + threadIdx.x * 4 + j;
        v[j] = (idx < N) ? cnt[idx] : 0u;
        s += v[j];
    }
    ls[threadIdx.x] = s;
    __syncthreads();
    if (threadIdx.x == 0) {
        unsigned acc = bsum[blockIdx.x];
        for (int i = 0; i < 256; i++) { unsigned t = ls[i]; ls[i] = acc; acc += t; }
    }
    __syncthreads();
    unsigned acc = ls[threadIdx.x];
#pragma unroll
    for (int j = 0; j < 4; j++) {
        int idx = base + threadIdx.x * 4 + j;
        if (idx < N) { off[idx] = (int)acc; cursor[idx] = (int)acc; }
        acc += v[j];
    }
    if (base + threadIdx.x * 4 <= N - 1 && N - 1 < base + threadIdx.x * 4 + 4) off[N] = E;
}

// ---------------- counting-sort placement: (row, norm) grouped by col ----------------
__global__ __launch_bounds__(256) void k_place(const int* __restrict__ row,
                                               const int* __restrict__ col,
                                               const float* __restrict__ dinv,
                                               int* __restrict__ cursor,
                                               int2* __restrict__ spack, int E) {
    int e = blockIdx.x * 256 + threadIdx.x;
    if (e >= E) return;
    int r = row[e], c = col[e];
    int pos = atomicAdd(&cursor[c], 1);
    spack[pos] = make_int2(r, __float_as_int(dinv[r] * dinv[c]));
}

// ---------------- weight prep: wT[n][k] = bf16(W[k][n]), 2 matrices ----------------
__global__ __launch_bounds__(256) void k_prepw(const float* __restrict__ W1,
                                               const float* __restrict__ W2,
                                               unsigned short* __restrict__ wT) {
    int m = blockIdx.x >> 4;                 // matrix 0..1
    int idx = (blockIdx.x & 15) * 256 + threadIdx.x;  // 0..4095 float4s
    const float* W = (m == 0) ? W1 : W2;
    unsigned short* T = wT + (size_t)m * 16384;
    int k = idx >> 5, n4 = (idx & 31) * 4;
    float4 v = *(const float4*)(W + (size_t)k * 128 + n4);
    T[(size_t)(n4 + 0) * 128 + k] = f2bf(v.x);
    T[(size_t)(n4 + 1) * 128 + k] = f2bf(v.y);
    T[(size_t)(n4 + 2) * 128 + k] = f2bf(v.z);
    T[(size_t)(n4 + 3) * 128 + k] = f2bf(v.w);
}

// ---------------- MFMA GEMM: Y[N,128] = X[N,128] @ W[128,128] -> bf16 ----------------
// MODE 0: f32 in. MODE 1: bf16 in with BN+leaky fused.
template <int MODE>
__global__ __launch_bounds__(256) void k_gemm_m(const void* __restrict__ Xv,
                                                const unsigned short* __restrict__ wT,
                                                const float* __restrict__ sums, float invN,
                                                const float* __restrict__ bnw,
                                                const float* __restrict__ bnb,
                                                void* __restrict__ Yv, int N) {
    __shared__ unsigned short xs[64][136];   // +8 pad: conflict-free b128 reads
    __shared__ float sc[128], sb[128];
    const int tid = threadIdx.x;
    if (MODE == 1) {
        if (tid < 128) {
            float mu = sums[tid] * invN;
            float var = sums[128 + tid] * invN - mu * mu;
            float s = rsqrtf(var + EPSV) * bnw[tid];
            sc[tid] = s;
            sb[tid] = bnb[tid] - mu * s;
        }
        __syncthreads();
    }
    const int base = blockIdx.x * 64;
    if (MODE == 1) {
        const unsigned short* Xh = (const unsigned short*)Xv;
        for (int i = tid; i < 1024; i += 256) {
            int r = i >> 4, c8 = (i & 15) * 8;
            int row = base + r; if (row >= N) row = N - 1;
            ushort8v v = *(const ushort8v*)(Xh + (size_t)row * 128 + c8);
            ushort8v o;
#pragma unroll
            for (int j = 0; j < 8; j++) {
                float f = fmaf(bf2f(v[j]), sc[c8 + j], sb[c8 + j]);
                f = f > 0.f ? f : SLOPE * f;
                o[j] = f2bf(f);
            }
            *(ushort8v*)(&xs[r][c8]) = o;
        }
    } else {
        const float* X = (const float*)Xv;
        for (int i = tid; i < 2048; i += 256) {
            int r = i >> 5, c4 = i & 31;
            int row = base + r; if (row >= N) row = N - 1;
            float4 v = ((const float4*)(X + (size_t)row * 128))[c4];
            ushort4 o;
            o.x = f2bf(v.x); o.y = f2bf(v.y); o.z = f2bf(v.z); o.w = f2bf(v.w);
            *(ushort4*)(&xs[r][c4 * 4]) = o;
        }
    }
    __syncthreads();

    const int lane = tid & 63;
    const int m0 = (tid >> 6) * 16;          // wave's 16 rows in tile
    const int mr = lane & 15;
    const int kg = lane >> 4;                // 0..3
    f32x4 acc[8];
#pragma unroll
    for (int nf = 0; nf < 8; nf++) acc[nf] = (f32x4){0.f, 0.f, 0.f, 0.f};

#pragma unroll
    for (int kt = 0; kt < 4; kt++) {
        bf16x8 a = *(const bf16x8*)(&xs[m0 + mr][kt * 32 + kg * 8]);
#pragma unroll
        for (int nf = 0; nf < 8; nf++) {
            bf16x8 b = *(const bf16x8*)(wT + (size_t)(nf * 16 + mr) * 128 + kt * 32 + kg * 8);
            acc[nf] = __builtin_amdgcn_mfma_f32_16x16x32_bf16(a, b, acc[nf], 0, 0, 0);
        }
    }

    // C/D layout: col = lane&15, row = (lane>>4)*4 + r; repack via LDS -> coalesced stores
    __syncthreads();
#pragma unroll
    for (int nf = 0; nf < 8; nf++) {
#pragma unroll
        for (int r = 0; r < 4; r++) {
            xs[m0 + kg * 4 + r][nf * 16 + mr] = f2bf(acc[nf][r]);
        }
    }
    __syncthreads();
    unsigned short* Yh = (unsigned short*)Yv;
    for (int i = tid; i < 1024; i += 256) {
        int r = i >> 4, c8 = (i & 15) * 8;
        int row = base + r;
        if (row < N)
            *(ushort8v*)(Yh + (size_t)row * 128 + c8) = *(const ushort8v*)(&xs[r][c8]);
    }
}

// ---------------- CSR aggregation: 16-lane group owns a node ----------------
// Batched 8-deep gathers (default cache policy); fused self-loop + bias + bf16 h + BN stats.
__global__ __launch_bounds__(256) void k_agg5(const unsigned short* __restrict__ xwh,
                                              const int* __restrict__ off,
                                              const int2* __restrict__ spack,
                                              const float* __restrict__ dinv,
                                              const float* __restrict__ bias,
                                              unsigned short* __restrict__ h,
                                              float* __restrict__ sums, int N) {
    __shared__ float ls1[128], ls2[128];
    const int tid = threadIdx.x;
    if (tid < 128) { ls1[tid] = 0.f; ls2[tid] = 0.f; }
    __syncthreads();

    const int q = tid & 15;
    const int grp = (blockIdx.x * 256 + tid) >> 4;
    const int nGrp = gridDim.x * 16;

    float bj[8];
#pragma unroll
    for (int j = 0; j < 8; j++) bj[j] = bias[q * 8 + j];
    float st1[8] = {0, 0, 0, 0, 0, 0, 0, 0};
    float st2[8] = {0, 0, 0, 0, 0, 0, 0, 0};

    for (int n = grp; n < N; n += nGrp) {
        const int s = off[n], e = off[n + 1];
        float a[8] = {0, 0, 0, 0, 0, 0, 0, 0};
        int i = s;
        for (; i + 8 <= e; i += 8) {
            int2 p0 = spack[i + 0], p1 = spack[i + 1], p2 = spack[i + 2], p3 = spack[i + 3];
            int2 p4 = spack[i + 4], p5 = spack[i + 5], p6 = spack[i + 6], p7 = spack[i + 7];
            ushort8v v0 = *(const ushort8v*)(xwh + (size_t)p0.x * 128 + q * 8);
            ushort8v v1 = *(const ushort8v*)(xwh + (size_t)p1.x * 128 + q * 8);
            ushort8v v2 = *(const ushort8v*)(xwh + (size_t)p2.x * 128 + q * 8);
            ushort8v v3 = *(const ushort8v*)(xwh + (size_t)p3.x * 128 + q * 8);
            ushort8v v4 = *(const ushort8v*)(xwh + (size_t)p4.x * 128 + q * 8);
            ushort8v v5 = *(const ushort8v*)(xwh + (size_t)p5.x * 128 + q * 8);
            ushort8v v6 = *(const ushort8v*)(xwh + (size_t)p6.x * 128 + q * 8);
            ushort8v v7 = *(const ushort8v*)(xwh + (size_t)p7.x * 128 + q * 8);
            float n0 = __int_as_float(p0.y), n1 = __int_as_float(p1.y);
            float n2 = __int_as_float(p2.y), n3 = __int_as_float(p3.y);
            float n4 = __int_as_float(p4.y), n5 = __int_as_float(p5.y);
            float n6 = __int_as_float(p6.y), n7 = __int_as_float(p7.y);
#pragma unroll
            for (int j = 0; j < 8; j++) {
                float t = fmaf(n0, bf2f(v0[j]), fmaf(n1, bf2f(v1[j]),
                          fmaf(n2, bf2f(v2[j]), n3 * bf2f(v3[j]))));
                float u = fmaf(n4, bf2f(v4[j]), fmaf(n5, bf2f(v5[j]),
                          fmaf(n6, bf2f(v6[j]), n7 * bf2f(v7[j]))));
                a[j] += t + u;
            }
        }
        for (; i + 4 <= e; i += 4) {
            int2 p0 = spack[i + 0], p1 = spack[i + 1], p2 = spack[i + 2], p3 = spack[i + 3];
            ushort8v v0 = *(const ushort8v*)(xwh + (size_t)p0.x * 128 + q * 8);
            ushort8v v1 = *(const ushort8v*)(xwh + (size_t)p1.x * 128 + q * 8);
            ushort8v v2 = *(const ushort8v*)(xwh + (size_t)p2.x * 128 + q * 8);
            ushort8v v3 = *(const ushort8v*)(xwh + (size_t)p3.x * 128 + q * 8);
            float n0 = __int_as_float(p0.y), n1 = __int_as_float(p1.y);
            float n2 = __int_as_float(p2.y), n3 = __int_as_float(p3.y);
#pragma unroll
            for (int j = 0; j < 8; j++) {
                a[j] += fmaf(n0, bf2f(v0[j]), fmaf(n1, bf2f(v1[j]),
                        fmaf(n2, bf2f(v2[j]), n3 * bf2f(v3[j]))));
            }
        }
        for (; i < e; ++i) {
            int2 p = spack[i];
            ushort8v v = *(const ushort8v*)(xwh + (size_t)p.x * 128 + q * 8);
            float nm = __int_as_float(p.y);
#pragma unroll
            for (int j = 0; j < 8; j++) a[j] = fmaf(nm, bf2f(v[j]), a[j]);
        }
        float dc = dinv[n];
        float sl = 2.f * dc * dc;
        ushort8v xv = *(const ushort8v*)(xwh + (size_t)n * 128 + q * 8);
        ushort8v ov;
#pragma unroll
        for (int j = 0; j < 8; j++) {
            float o = fmaf(sl, bf2f(xv[j]), a[j]) + bj[j];
            st1[j] += o;
            st2[j] += o * o;
            ov[j] = f2bf(o);
        }
        *(ushort8v*)(h + (size_t)n * 128 + q * 8) = ov;
    }
#pragma unroll
    for (int j = 0; j < 8; j++) {
        atomicAdd(&ls1[q * 8 + j], st1[j]);
        atomicAdd(&ls2[q * 8 + j], st2[j]);
    }
    __syncthreads();
    if (tid < 128) {
        atomicAdd(&sums[tid], ls1[tid]);
        atomicAdd(&sums[128 + tid], ls2[tid]);
    }
}

// ---------------- fused tail: BN2+leaky+segment-max+final GEMM ----------------
// one wave per graph; batch is sorted -> binary search node range
__global__ __launch_bounds__(256) void k_tail(const unsigned short* __restrict__ h,
                                              const int* __restrict__ batch,
                                              const float* __restrict__ sums, float invN,
                                              const float* __restrict__ bnw,
                                              const float* __restrict__ bnb,
                                              const float* __restrict__ Wf,
                                              const float* __restrict__ bf,
                                              float* __restrict__ out, int N, int G) {
    const int lane = threadIdx.x & 63;
    const int g = blockIdx.x * 4 + (threadIdx.x >> 6);
    if (g >= G) return;
    const int f0 = lane, f1 = lane + 64;
    float mu0 = sums[f0] * invN;
    float var0 = sums[128 + f0] * invN - mu0 * mu0;
    float sc0 = rsqrtf(var0 + EPSV) * bnw[f0];
    float sb0 = bnb[f0] - mu0 * sc0;
    float mu1 = sums[f1] * invN;
    float var1 = sums[128 + f1] * invN - mu1 * mu1;
    float sc1 = rsqrtf(var1 + EPSV) * bnw[f1];
    float sb1 = bnb[f1] - mu1 * sc1;

    int lo, hi;
    { int a = 0, b = N; while (a < b) { int m = (a + b) >> 1; if (batch[m] < g) a = m + 1; else b = m; } lo = a; }
    { int a = lo, b = N; while (a < b) { int m = (a + b) >> 1; if (batch[m] < g + 1) a = m + 1; else b = m; } hi = a; }

    float m0 = -__builtin_inff(), m1 = -__builtin_inff();
    for (int n = lo; n < hi; n++) {
        float v0 = fmaf(bf2f(h[(size_t)n * 128 + f0]), sc0, sb0);
        float v1 = fmaf(bf2f(h[(size_t)n * 128 + f1]), sc1, sb1);
        v0 = v0 > 0.f ? v0 : SLOPE * v0;
        v1 = v1 > 0.f ? v1 : SLOPE * v1;
        m0 = fmaxf(m0, v0);
        m1 = fmaxf(m1, v1);
    }
    if (lo >= hi) { m0 = 0.f; m1 = 0.f; }  // empty graph -> pooled 0

    float o0 = bf[f0], o1 = bf[f1];
    for (int k = 0; k < 64; k++) {
        float vk = __shfl(m0, k, 64);
        o0 = fmaf(vk, Wf[(size_t)k * 128 + f0], o0);
        o1 = fmaf(vk, Wf[(size_t)k * 128 + f1], o1);
    }
    for (int k = 0; k < 64; k++) {
        float vk = __shfl(m1, k, 64);
        o0 = fmaf(vk, Wf[(size_t)(k + 64) * 128 + f0], o0);
        o1 = fmaf(vk, Wf[(size_t)(k + 64) * 128 + f1], o1);
    }
    out[(size_t)g * 128 + f0] = o0;
    out[(size_t)g * 128 + f1] = o1;
}

extern "C" void kernel_launch(void* const* d_in, const int* in_sizes, int n_in,
                              void* d_out, int out_size, void* d_ws, size_t ws_size,
                              hipStream_t stream) {
    const float* x     = (const float*)d_in[0];
    const int*   ei    = (const int*)d_in[1];
    const int*   batch = (const int*)d_in[2];
    const float* W1    = (const float*)d_in[3];
    const float* b1    = (const float*)d_in[4];
    const float* bn1w  = (const float*)d_in[5];
    const float* bn1b  = (const float*)d_in[6];
    const float* W2    = (const float*)d_in[7];
    const float* b2    = (const float*)d_in[8];
    const float* bn2w  = (const float*)d_in[9];
    const float* bn2b  = (const float*)d_in[10];
    const float* Wf    = (const float*)d_in[11];
    const float* bf    = (const float*)d_in[12];

    const int N = in_sizes[0] / 128;
    const int E = in_sizes[1] / 2;
    const int G = out_size / 128;
    const int* rowp = ei;
    const int* colp = ei + E;
    float* out = (float*)d_out;
    const float invN = 1.0f / N;

    char* w = (char*)d_ws;
    unsigned short* bufAh = (unsigned short*)w; w += (size_t)N * 128 * 2;  // bf16 xw
    unsigned short* bufBh = (unsigned short*)w; w += (size_t)N * 128 * 2;  // bf16 h
    float*    dinv   = (float*)w;    w += (size_t)N * 4;
    unsigned* cnt    = (unsigned*)w; w += (size_t)N * 4;
    int*      cursor = (int*)w;      w += (size_t)N * 4;
    int*      off    = (int*)w;      w += (size_t)(N + 4) * 4;
    unsigned* bsum   = (unsigned*)w; w += 1024 * 4;
    int2*     spack  = (int2*)w;     w += (size_t)E * 8;
    float*    sums   = (float*)w;    w += 512 * 4;                         // sums1 | sums2
    unsigned short* wT = (unsigned short*)w; w += 2 * 16384 * 2;           // wT1|wT2

    float* sums1 = sums;
    float* sums2 = sums + 256;
    const int nb = (N + 1023) / 1024;

    // ---- prep (graph CSR + bf16 transposed weights) ----
    hipMemsetAsync(cnt, 0, (size_t)N * 4, stream);
    hipMemsetAsync(sums, 0, 512 * 4, stream);
    k_prepw<<<32, 256, 0, stream>>>(W1, W2, wT);
    k_count<<<(E + 255) / 256, 256, 0, stream>>>(colp, cnt, E);
    k_chunk_sum<<<nb, 256, 0, stream>>>(cnt, N, bsum, dinv);
    k_scan_bsum<<<1, 128, 0, stream>>>(bsum, nb);
    k_scan_chunks<<<nb, 256, 0, stream>>>(cnt, N, bsum, off, cursor, E);
    k_place<<<(E + 255) / 256, 256, 0, stream>>>(rowp, colp, dinv, cursor, spack, E);

    const int aggBlocks = 2048;
    const int gemmGrid = (N + 63) / 64;

    // ---- layer 1 ----
    k_gemm_m<0><<<gemmGrid, 256, 0, stream>>>(x, wT, nullptr, 0.f, nullptr, nullptr,
                                              bufAh, N);
    k_agg5<<<aggBlocks, 256, 0, stream>>>(bufAh, off, spack, dinv, b1, bufBh, sums1, N);

    // ---- layer 2 (BN1 fused into GEMM staging, bf16 input) ----
    k_gemm_m<1><<<gemmGrid, 256, 0, stream>>>(bufBh, wT + 16384, sums1, invN, bn1w, bn1b,
                                              bufAh, N);
    k_agg5<<<aggBlocks, 256, 0, stream>>>(bufAh, off, spack, dinv, b2, bufBh, sums2, N);

    // ---- fused tail: BN2 + leaky + segment-max + final GEMM ----
    k_tail<<<(G + 3) / 4, 256, 0, stream>>>(bufBh, batch, sums2, invN, bn2w, bn2b,
                                            Wf, bf, out, N, G);
}